// Round 4
// baseline (908.083 us; speedup 1.0000x reference)
//
#include <hip/hip_runtime.h>
#include <hip/hip_bf16.h>

#define DEV __device__ __forceinline__

typedef short bf16x8 __attribute__((ext_vector_type(8)));
typedef float f32x16 __attribute__((ext_vector_type(16)));

static constexpr int FDIM  = 64;
static constexpr int HH    = 128;           // hidden/out dim
static constexpr int K1RAW = 2 * FDIM + 3;  // 131
static constexpr int K1    = 144;           // padded K for layer 1 (mult of 16)
static constexpr int KS1   = K1 / 16;       // 9 k-steps
static constexpr int TM    = 128;           // edges per block tile

static constexpr int MSTR  = 2 * K1;        // msg row stride bytes (288)
static constexpr int L_TOT = TM * MSTR + TM * 4;   // 37376

static constexpr int WT1_ELEMS = HH * K1;          // 18432
static constexpr int WT2_ELEMS = HH * HH;          // 16384
static constexpr int WT_TOTAL  = WT1_ELEMS + 2 * WT2_ELEMS; // 51200

DEV unsigned pack2(float a, float b) {
    union { __hip_bfloat162 h; unsigned u; } cv;
    cv.h.x = __float2bfloat16(a);
    cv.h.y = __float2bfloat16(b);
    return cv.u;
}
DEV unsigned short f2bf(float f) {
    union { __hip_bfloat16 h; unsigned short u; } cv;
    cv.h = __float2bfloat16(f);
    return cv.u;
}
// chunk swizzle (16B chunks within a 288B row): chunks 0..15 XOR low-3 bits
// with row; chunks 16..17 XOR 1 bit (stay in range).
DEV int swz_msg(int c, int r) { const int m = (c < 16) ? 7 : 1; return (c & ~m) | ((c ^ r) & m); }

// ---------------- input bf16 conversion ----------------
__global__ void k_cvt(const float* __restrict__ src, unsigned short* __restrict__ dst, int n8) {
    int i = blockIdx.x * 256 + threadIdx.x;
    if (i < n8) {
        float4 a = *(const float4*)(src + (size_t)i * 8);
        float4 b = *(const float4*)(src + (size_t)i * 8 + 4);
        uint4 o;
        o.x = pack2(a.x, a.y); o.y = pack2(a.z, a.w);
        o.z = pack2(b.x, b.y); o.w = pack2(b.z, b.w);
        *(uint4*)(dst + (size_t)i * 8) = o;
    }
}

// ---------------- weight transpose + bf16 convert ----------------
__global__ void k_wprep(const float* __restrict__ W1, const float* __restrict__ W2,
                        const float* __restrict__ W3, unsigned short* __restrict__ wt) {
    int i = blockIdx.x * 256 + threadIdx.x;
    if (i < WT1_ELEMS) {
        int n = i / K1, k = i % K1;
        float v = (k < K1RAW) ? W1[k * HH + n] : 0.f;
        wt[i] = f2bf(v);
    } else if (i < WT1_ELEMS + WT2_ELEMS) {
        int j = i - WT1_ELEMS; int n = j / HH, k = j % HH;
        wt[i] = f2bf(W2[k * HH + n]);
    } else if (i < WT_TOTAL) {
        int j = i - WT1_ELEMS - WT2_ELEMS; int n = j / HH, k = j % HH;
        wt[i] = f2bf(W3[k * HH + n]);
    }
}

// ---------------- CSR build: hist -> scan -> fill ----------------
__global__ void k_hist(const int* __restrict__ edst, int* __restrict__ cnt, int E) {
    int e = blockIdx.x * 256 + threadIdx.x;
    if (e < E) atomicAdd(&cnt[edst[e]], 1);
}

__global__ void k_scan_part(const int* __restrict__ cnt, int* __restrict__ partial, int n2) {
    __shared__ int sm[256];
    int t = threadIdx.x;
    int base = blockIdx.x * 1024 + t * 4;
    int s = 0;
#pragma unroll
    for (int j = 0; j < 4; j++) { int idx = base + j; if (idx < n2) s += cnt[idx]; }
    sm[t] = s; __syncthreads();
    for (int off = 128; off > 0; off >>= 1) {
        if (t < off) sm[t] += sm[t + off];
        __syncthreads();
    }
    if (t == 0) partial[blockIdx.x] = sm[0];
}

__global__ void k_scan_top(int* __restrict__ partial, int nb) {
    __shared__ int sm[256];
    int t = threadIdx.x;
    int v = (t < nb) ? partial[t] : 0;
    sm[t] = v; __syncthreads();
    for (int off = 1; off < 256; off <<= 1) {
        int add = (t >= off) ? sm[t - off] : 0;
        __syncthreads();
        sm[t] += add;
        __syncthreads();
    }
    if (t < nb) partial[t] = sm[t] - v;   // exclusive
}

__global__ void k_scan_down(const int* __restrict__ cnt, const int* __restrict__ partial,
                            int* __restrict__ cursor, int n2) {
    __shared__ int sm[256];
    int t = threadIdx.x;
    int base = blockIdx.x * 1024 + t * 4;
    int c[4]; int s = 0;
#pragma unroll
    for (int j = 0; j < 4; j++) { int idx = base + j; c[j] = (idx < n2) ? cnt[idx] : 0; s += c[j]; }
    sm[t] = s; __syncthreads();
    for (int off = 1; off < 256; off <<= 1) {
        int add = (t >= off) ? sm[t - off] : 0;
        __syncthreads();
        sm[t] += add;
        __syncthreads();
    }
    int run = partial[blockIdx.x] + (sm[t] - s);
#pragma unroll
    for (int j = 0; j < 4; j++) {
        int idx = base + j;
        if (idx < n2) cursor[idx] = run;
        run += c[j];
    }
}

__global__ void k_fill(const int* __restrict__ edst, int* __restrict__ cursor,
                       int* __restrict__ csr_e, int* __restrict__ csr_d, int E) {
    int e = blockIdx.x * 256 + threadIdx.x;
    if (e < E) {
        int d = edst[e];
        int p = atomicAdd(&cursor[d], 1);
        csr_e[p] = e;
        csr_d[p] = d;
    }
}

// ---------------- fused MLP (registerized) + segment-max ----------------
DEV f32x16 zerov() {
    f32x16 v;
#pragma unroll
    for (int i = 0; i < 16; i++) v[i] = 0.f;
    return v;
}

// acc -> bias+ReLU -> packed bf16 pairs. pk[2u+p] covers feats 8u+4*hh+{2p,2p+1}
// (u = 4*t+g: tile t, reg-group g).
DEV void pk_prep(const f32x16 a[4], const float* __restrict__ bias, int hh, unsigned pk[32]) {
#pragma unroll
    for (int u = 0; u < 16; u++) {
        const int t = u >> 2, g = u & 3;
        float4 bv = *(const float4*)(bias + 8 * u + 4 * hh);
        float v0 = fmaxf(a[t][4 * g + 0] + bv.x, 0.f);
        float v1 = fmaxf(a[t][4 * g + 1] + bv.y, 0.f);
        float v2 = fmaxf(a[t][4 * g + 2] + bv.z, 0.f);
        float v3 = fmaxf(a[t][4 * g + 3] + bv.w, 0.f);
        pk[2 * u + 0] = pack2(v0, v1);
        pk[2 * u + 1] = pack2(v2, v3);
    }
}

// One hidden layer entirely in registers: B-fragments built from previous
// layer's packed activations via lane^32 exchange. K=128, 8 k-steps.
DEV void layer_reg(const unsigned short* __restrict__ wtl, const unsigned pk[32],
                   int l31, int hh, f32x16 c[4]) {
#pragma unroll
    for (int ks = 0; ks < 8; ks++) {
        const int u0 = 2 * ks, u1 = 2 * ks + 1;
        int s0 = __shfl_xor((int)pk[2 * u1 + 0], 32, 64);
        int s1 = __shfl_xor((int)pk[2 * u1 + 1], 32, 64);
        int s2 = __shfl_xor((int)pk[2 * u0 + 0], 32, 64);
        int s3 = __shfl_xor((int)pk[2 * u0 + 1], 32, 64);
        union { unsigned u[4]; bf16x8 v; } B;
        B.u[0] = (hh == 0) ? pk[2 * u0 + 0] : (unsigned)s0;
        B.u[1] = (hh == 0) ? pk[2 * u0 + 1] : (unsigned)s1;
        B.u[2] = (hh == 0) ? (unsigned)s2 : pk[2 * u1 + 0];
        B.u[3] = (hh == 0) ? (unsigned)s3 : pk[2 * u1 + 1];
#pragma unroll
        for (int t = 0; t < 4; t++) {
            bf16x8 A = *(const bf16x8*)(wtl + (t * 32 + l31) * HH + ks * 16 + 8 * hh);
            c[t] = __builtin_amdgcn_mfma_f32_32x32x16_bf16(A, B.v, c[t], 0, 0, 0);
        }
    }
}

template <bool SORTED, bool BF16SRC>
__global__ __launch_bounds__(256, 3) void k_main(
    const float* __restrict__ x1f, const float* __restrict__ x1p,
    const float* __restrict__ x2f, const float* __restrict__ x2p,
    const char* __restrict__ xb1, const char* __restrict__ xb2,
    const float* __restrict__ b1, const float* __restrict__ b2, const float* __restrict__ b3,
    const unsigned short* __restrict__ wt,
    const int* __restrict__ csr_e, const int* __restrict__ csr_d,
    const int* __restrict__ edge_src, const int* __restrict__ edge_dst,
    float* __restrict__ out, int E) {
    __shared__ __align__(16) char sm[L_TOT];
    char* msg = sm;
    int*  dl  = (int*)(sm + TM * MSTR);

    const int tid  = threadIdx.x;
    const int lane = tid & 63;
    const int wv   = tid >> 6;    // 0..3
    const int l31  = lane & 31;
    const int hh   = lane >> 5;
    const int eb   = blockIdx.x * TM;

    // ---------- stage msg (bf16, swizzled); 2 threads per edge-row ----------
    {
        const int r   = tid >> 1;   // 0..127
        const int sub = tid & 1;
        const int slot = eb + r;
        const bool ok = slot < E;
        int e = 0, d = 0, s = 0;
        if (ok) {
            if (SORTED) { e = csr_e[slot]; d = csr_d[slot]; }
            else        { e = slot;        d = edge_dst[e]; }
            s = edge_src[e];
        }
        if (sub == 0) dl[r] = ok ? d : -1;
        char* row = msg + r * MSTR;
        const int c0 = sub * 8;
#pragma unroll
        for (int i = 0; i < 8; i++) {
            const int c = c0 + i;                 // chunk 0..15 (8 feats each)
            uint4 v; v.x = v.y = v.z = v.w = 0u;
            if (ok) {
                if (BF16SRC) {
                    const char* base = (sub == 0) ? (xb2 + (size_t)d * (2 * FDIM))
                                                  : (xb1 + (size_t)s * (2 * FDIM));
                    v = *(const uint4*)(base + i * 16);
                } else {
                    const float* base = (sub == 0) ? (x2f + (size_t)d * FDIM)
                                                   : (x1f + (size_t)s * FDIM);
                    float4 a = *(const float4*)(base + i * 8);
                    float4 b = *(const float4*)(base + i * 8 + 4);
                    v.x = pack2(a.x, a.y); v.y = pack2(a.z, a.w);
                    v.z = pack2(b.x, b.y); v.w = pack2(b.z, b.w);
                }
            }
            *(uint4*)(row + swz_msg(c, r) * 16) = v;
        }
        if (sub == 1) {
            float dx = 0.f, dy = 0.f, dz = 0.f;
            if (ok) {
                dx = x1p[s * 3 + 0] - x2p[d * 3 + 0];
                dy = x1p[s * 3 + 1] - x2p[d * 3 + 1];
                dz = x1p[s * 3 + 2] - x2p[d * 3 + 2];
            }
            uint4 v; v.x = pack2(dx, dy); v.y = pack2(dz, 0.f); v.z = 0u; v.w = 0u;
            *(uint4*)(row + swz_msg(16, r) * 16) = v;   // feats 128..135
            uint4 z; z.x = z.y = z.z = z.w = 0u;
            *(uint4*)(row + swz_msg(17, r) * 16) = z;   // feats 136..143
        }
    }
    __syncthreads();

    const int myrow = wv * 32 + l31;        // this lane's edge row (as MFMA col)
    const char* mrow = msg + myrow * MSTR;

    // ---- layer 1: B from LDS msg (K=144), A from wt1 ----
    f32x16 a[4];
    a[0] = zerov(); a[1] = zerov(); a[2] = zerov(); a[3] = zerov();
#pragma unroll
    for (int ks = 0; ks < KS1; ks++) {
        bf16x8 B = *(const bf16x8*)(mrow + swz_msg(2 * ks + hh, myrow) * 16);
#pragma unroll
        for (int t = 0; t < 4; t++) {
            bf16x8 A = *(const bf16x8*)(wt + (t * 32 + l31) * K1 + ks * 16 + 8 * hh);
            a[t] = __builtin_amdgcn_mfma_f32_32x32x16_bf16(A, B, a[t], 0, 0, 0);
        }
    }

    unsigned pk[32];
    pk_prep(a, b1, hh, pk);

    // ---- layer 2: fully in registers ----
    f32x16 c[4];
    c[0] = zerov(); c[1] = zerov(); c[2] = zerov(); c[3] = zerov();
    layer_reg(wt + WT1_ELEMS, pk, l31, hh, c);
    pk_prep(c, b2, hh, pk);

    // ---- layer 3: fully in registers ----
    a[0] = zerov(); a[1] = zerov(); a[2] = zerov(); a[3] = zerov();
    layer_reg(wt + WT1_ELEMS + WT2_ELEMS, pk, l31, hh, a);
    pk_prep(a, b3, hh, pk);

    // ---- write h3 (bf16) into this wave's own (dead) msg rows ----
    {
        char* hrow = msg + myrow * MSTR;
#pragma unroll
        for (int u = 0; u < 16; u++) {
            uint2 w; w.x = pk[2 * u + 0]; w.y = pk[2 * u + 1];
            *(uint2*)(hrow + swz_msg(u, myrow) * 16 + 8 * hh) = w;
        }
    }
    __syncthreads();

    // ---------- segment-max reduce (dst-sorted runs -> few atomics) ----------
    {
        const int cpair = tid & 63;   // feature pair: features 2*cpair, 2*cpair+1
        const int strip = tid >> 6;   // 4 strips of 32 rows
        const int r0 = strip * 32;
        int curd = dl[r0];
        float m0 = 0.f, m1 = 0.f;
        for (int r = r0; r < r0 + 32; r++) {
            int d = dl[r];
            if (d != curd) {
                if (curd >= 0) {
                    if (m0 > 0.f) atomicMax((int*)out + (size_t)curd * HH + 2 * cpair,     __float_as_int(m0));
                    if (m1 > 0.f) atomicMax((int*)out + (size_t)curd * HH + 2 * cpair + 1, __float_as_int(m1));
                }
                curd = d; m0 = 0.f; m1 = 0.f;
            }
            unsigned w = *(const unsigned*)(msg + r * MSTR + swz_msg(cpair >> 2, r) * 16 + (cpair & 3) * 4);
            m0 = fmaxf(m0, __uint_as_float(w << 16));
            m1 = fmaxf(m1, __uint_as_float(w & 0xffff0000u));
        }
        if (curd >= 0) {
            if (m0 > 0.f) atomicMax((int*)out + (size_t)curd * HH + 2 * cpair,     __float_as_int(m0));
            if (m1 > 0.f) atomicMax((int*)out + (size_t)curd * HH + 2 * cpair + 1, __float_as_int(m1));
        }
    }
}

extern "C" void kernel_launch(void* const* d_in, const int* in_sizes, int n_in,
                              void* d_out, int out_size, void* d_ws, size_t ws_size,
                              hipStream_t stream) {
    const float* x1f = (const float*)d_in[0];
    const float* x1p = (const float*)d_in[1];
    const float* x2f = (const float*)d_in[2];
    const float* x2p = (const float*)d_in[3];
    const float* W1  = (const float*)d_in[4];
    const float* b1  = (const float*)d_in[5];
    const float* W2  = (const float*)d_in[6];
    const float* b2  = (const float*)d_in[7];
    const float* W3  = (const float*)d_in[8];
    const float* b3  = (const float*)d_in[9];
    const int* esrc  = (const int*)d_in[10];
    const int* edst  = (const int*)d_in[11];
    const int E  = in_sizes[10];
    const int N1 = in_sizes[1] / 3;
    const int N2 = in_sizes[3] / 3;
    float* out = (float*)d_out;

    // workspace layout
    size_t off = 0;
    auto take = [&](size_t bytes) { size_t o = off; off = (off + bytes + 255) & ~(size_t)255; return o; };
    size_t o_cnt = take(4 * (size_t)N2);
    size_t o_cur = take(4 * (size_t)N2);
    size_t o_par = take(4 * 256);
    size_t o_ce  = take(4 * (size_t)E);
    size_t o_cd  = take(4 * (size_t)E);
    size_t o_wt  = take(2 * (size_t)WT_TOTAL);
    size_t need_csr = off;
    size_t o_x1  = take(2 * (size_t)N1 * FDIM);
    size_t o_x2  = take(2 * (size_t)N2 * FDIM);
    size_t need_bf = off;

    const int NB = (N2 + 1023) / 1024;
    bool use_csr = (need_csr <= ws_size) && (NB <= 256);
    bool use_bf  = (need_bf <= ws_size);

    char* ws = (char*)d_ws;
    unsigned short* wt = use_csr ? (unsigned short*)(ws + o_wt) : (unsigned short*)ws;
    int* cnt    = (int*)(ws + o_cnt);
    int* cursor = (int*)(ws + o_cur);
    int* part   = (int*)(ws + o_par);
    int* csr_e  = (int*)(ws + o_ce);
    int* csr_d  = (int*)(ws + o_cd);
    char* xb1   = ws + o_x1;
    char* xb2   = ws + o_x2;

    // output init: zero aggregate region, copy x2_pos into tail
    (void)hipMemsetAsync(out, 0, (size_t)N2 * HH * 4, stream);
    (void)hipMemcpyAsync(out + (size_t)N2 * HH, x2p, (size_t)N2 * 3 * 4,
                         hipMemcpyDeviceToDevice, stream);

    k_wprep<<<(WT_TOTAL + 255) / 256, 256, 0, stream>>>(W1, W2, W3, wt);

    if (use_bf) {
        int n8_1 = N1 * FDIM / 8, n8_2 = N2 * FDIM / 8;
        k_cvt<<<(n8_1 + 255) / 256, 256, 0, stream>>>(x1f, (unsigned short*)xb1, n8_1);
        k_cvt<<<(n8_2 + 255) / 256, 256, 0, stream>>>(x2f, (unsigned short*)xb2, n8_2);
    }

    const int grid = (E + TM - 1) / TM;
    if (use_csr) {
        (void)hipMemsetAsync(cnt, 0, 4 * (size_t)N2, stream);
        k_hist<<<(E + 255) / 256, 256, 0, stream>>>(edst, cnt, E);
        k_scan_part<<<NB, 256, 0, stream>>>(cnt, part, N2);
        k_scan_top<<<1, 256, 0, stream>>>(part, NB);
        k_scan_down<<<NB, 256, 0, stream>>>(cnt, part, cursor, N2);
        k_fill<<<(E + 255) / 256, 256, 0, stream>>>(edst, cursor, csr_e, csr_d, E);
        if (use_bf)
            k_main<true, true><<<grid, 256, 0, stream>>>(
                x1f, x1p, x2f, x2p, xb1, xb2, b1, b2, b3, wt, csr_e, csr_d, esrc, edst, out, E);
        else
            k_main<true, false><<<grid, 256, 0, stream>>>(
                x1f, x1p, x2f, x2p, xb1, xb2, b1, b2, b3, wt, csr_e, csr_d, esrc, edst, out, E);
    } else {
        if (use_bf)
            k_main<false, true><<<grid, 256, 0, stream>>>(
                x1f, x1p, x2f, x2p, xb1, xb2, b1, b2, b3, wt, edst, edst, esrc, edst, out, E);
        else
            k_main<false, false><<<grid, 256, 0, stream>>>(
                x1f, x1p, x2f, x2p, xb1, xb2, b1, b2, b3, wt, edst, edst, esrc, edst, out, E);
    }
}

// Round 5
// 824.604 us; speedup vs baseline: 1.1012x; 1.1012x over previous
//
#include <hip/hip_runtime.h>
#include <hip/hip_bf16.h>

#define DEV __device__ __forceinline__

typedef short bf16x8 __attribute__((ext_vector_type(8)));
typedef float f32x16 __attribute__((ext_vector_type(16)));

static constexpr int FDIM  = 64;
static constexpr int HH    = 128;           // hidden/out dim
static constexpr int K1RAW = 2 * FDIM + 3;  // 131
static constexpr int K1    = 144;           // padded K for layer 1 (mult of 16)
static constexpr int KS1   = K1 / 16;       // 9 k-steps
static constexpr int KS2   = HH / 16;       // 8 k-steps
static constexpr int TM    = 64;            // edges per block tile

static constexpr int MSTR  = 2 * K1;        // msg row stride bytes (288)
static constexpr int HSTR  = 2 * HH;        // h row stride bytes (256)
static constexpr int L_MSG = 0;
static constexpr int L_H   = TM * MSTR;            // 18432
static constexpr int L_DST = L_H + TM * HSTR;      // 34816
static constexpr int L_TOT = L_DST + TM * 4;       // 35072

static constexpr int WT1_ELEMS = HH * K1;          // 18432
static constexpr int WT2_ELEMS = HH * HH;          // 16384
static constexpr int WT_TOTAL  = WT1_ELEMS + 2 * WT2_ELEMS; // 51200

DEV unsigned pack2(float a, float b) {
    union { __hip_bfloat162 h; unsigned u; } cv;
    cv.h.x = __float2bfloat16(a);
    cv.h.y = __float2bfloat16(b);
    return cv.u;
}
DEV unsigned short f2bf(float f) {
    union { __hip_bfloat16 h; unsigned short u; } cv;
    cv.h = __float2bfloat16(f);
    return cv.u;
}
// chunk swizzle (16B chunks within a 288B row): chunks 0..15 XOR low-3 bits
// with row; chunks 16..17 XOR 1 bit (stay in range).
DEV int swz_msg(int c, int r) { const int m = (c < 16) ? 7 : 1; return (c & ~m) | ((c ^ r) & m); }
DEV int swz_h(int c, int r)   { return (c & ~7) | ((c ^ r) & 7); }

// ---------------- input bf16 conversion ----------------
__global__ void k_cvt(const float* __restrict__ src, unsigned short* __restrict__ dst, int n8) {
    int i = blockIdx.x * 256 + threadIdx.x;
    if (i < n8) {
        float4 a = *(const float4*)(src + (size_t)i * 8);
        float4 b = *(const float4*)(src + (size_t)i * 8 + 4);
        uint4 o;
        o.x = pack2(a.x, a.y); o.y = pack2(a.z, a.w);
        o.z = pack2(b.x, b.y); o.w = pack2(b.z, b.w);
        *(uint4*)(dst + (size_t)i * 8) = o;
    }
}

// ---------------- weight transpose + bf16 convert ----------------
__global__ void k_wprep(const float* __restrict__ W1, const float* __restrict__ W2,
                        const float* __restrict__ W3, unsigned short* __restrict__ wt) {
    int i = blockIdx.x * 256 + threadIdx.x;
    if (i < WT1_ELEMS) {
        int n = i / K1, k = i % K1;
        float v = (k < K1RAW) ? W1[k * HH + n] : 0.f;
        wt[i] = f2bf(v);
    } else if (i < WT1_ELEMS + WT2_ELEMS) {
        int j = i - WT1_ELEMS; int n = j / HH, k = j % HH;
        wt[i] = f2bf(W2[k * HH + n]);
    } else if (i < WT_TOTAL) {
        int j = i - WT1_ELEMS - WT2_ELEMS; int n = j / HH, k = j % HH;
        wt[i] = f2bf(W3[k * HH + n]);
    }
}

// ---------------- CSR build: hist -> scan -> fill ----------------
__global__ void k_hist(const int* __restrict__ edst, int* __restrict__ cnt, int E) {
    int e = blockIdx.x * 256 + threadIdx.x;
    if (e < E) atomicAdd(&cnt[edst[e]], 1);
}

__global__ void k_scan_part(const int* __restrict__ cnt, int* __restrict__ partial, int n2) {
    __shared__ int sm[256];
    int t = threadIdx.x;
    int base = blockIdx.x * 1024 + t * 4;
    int s = 0;
#pragma unroll
    for (int j = 0; j < 4; j++) { int idx = base + j; if (idx < n2) s += cnt[idx]; }
    sm[t] = s; __syncthreads();
    for (int off = 128; off > 0; off >>= 1) {
        if (t < off) sm[t] += sm[t + off];
        __syncthreads();
    }
    if (t == 0) partial[blockIdx.x] = sm[0];
}

__global__ void k_scan_top(int* __restrict__ partial, int nb) {
    __shared__ int sm[256];
    int t = threadIdx.x;
    int v = (t < nb) ? partial[t] : 0;
    sm[t] = v; __syncthreads();
    for (int off = 1; off < 256; off <<= 1) {
        int add = (t >= off) ? sm[t - off] : 0;
        __syncthreads();
        sm[t] += add;
        __syncthreads();
    }
    if (t < nb) partial[t] = sm[t] - v;   // exclusive
}

__global__ void k_scan_down(const int* __restrict__ cnt, const int* __restrict__ partial,
                            int* __restrict__ cursor, int n2) {
    __shared__ int sm[256];
    int t = threadIdx.x;
    int base = blockIdx.x * 1024 + t * 4;
    int c[4]; int s = 0;
#pragma unroll
    for (int j = 0; j < 4; j++) { int idx = base + j; c[j] = (idx < n2) ? cnt[idx] : 0; s += c[j]; }
    sm[t] = s; __syncthreads();
    for (int off = 1; off < 256; off <<= 1) {
        int add = (t >= off) ? sm[t - off] : 0;
        __syncthreads();
        sm[t] += add;
        __syncthreads();
    }
    int run = partial[blockIdx.x] + (sm[t] - s);
#pragma unroll
    for (int j = 0; j < 4; j++) {
        int idx = base + j;
        if (idx < n2) cursor[idx] = run;
        run += c[j];
    }
}

__global__ void k_fill(const int* __restrict__ edst, int* __restrict__ cursor,
                       int* __restrict__ csr_e, int* __restrict__ csr_d, int E) {
    int e = blockIdx.x * 256 + threadIdx.x;
    if (e < E) {
        int d = edst[e];
        int p = atomicAdd(&cursor[d], 1);
        csr_e[p] = e;
        csr_d[p] = d;
    }
}

// ---------------- fused MLP + segment-max ----------------
DEV f32x16 zerov() {
    f32x16 v;
#pragma unroll
    for (int i = 0; i < 16; i++) v[i] = 0.f;
    return v;
}

// store one wave's 32x32 acc tile (bias+ReLU+bf16) into LDS buffer
template <int STRIDE>
DEV void tile_store(f32x16 acc, const float* __restrict__ bias, char* __restrict__ hb,
                    int rt, int ct, int l31, int hh) {
    const int r = ct * 32 + l31;
#pragma unroll
    for (int g = 0; g < 4; g++) {
        // regs 4g..4g+3 hold features rt*32 + 8g + 4hh + {0..3}
        float4 bv = *(const float4*)(bias + rt * 32 + 8 * g + 4 * hh);
        float v0 = fmaxf(acc[4 * g + 0] + bv.x, 0.f);
        float v1 = fmaxf(acc[4 * g + 1] + bv.y, 0.f);
        float v2 = fmaxf(acc[4 * g + 2] + bv.z, 0.f);
        float v3 = fmaxf(acc[4 * g + 3] + bv.w, 0.f);
        uint2 w; w.x = pack2(v0, v1); w.y = pack2(v2, v3);
        *(uint2*)(hb + r * STRIDE + swz_h(4 * rt + g, r) * 16 + 8 * hh) = w;
    }
}

// one K=128 layer: B from LDS (stride/swz_h), A from global weights
template <int STRIDE>
DEV f32x16 layer128(const unsigned short* __restrict__ wtl, const char* __restrict__ src,
                    int rt, int ct, int l31, int hh) {
    f32x16 acc = zerov();
#pragma unroll
    for (int ks = 0; ks < KS2; ks++) {
        bf16x8 A = *(const bf16x8*)(wtl + (rt * 32 + l31) * HH + ks * 16 + 8 * hh);
        const int r = ct * 32 + l31;
        bf16x8 B = *(const bf16x8*)(src + r * STRIDE + swz_h(2 * ks + hh, r) * 16);
        acc = __builtin_amdgcn_mfma_f32_32x32x16_bf16(A, B, acc, 0, 0, 0);
    }
    return acc;
}

template <bool SORTED, bool BF16SRC>
__global__ __launch_bounds__(512, 8) void k_main(
    const float* __restrict__ x1f, const float* __restrict__ x1p,
    const float* __restrict__ x2f, const float* __restrict__ x2p,
    const char* __restrict__ xb1, const char* __restrict__ xb2,
    const float* __restrict__ b1, const float* __restrict__ b2, const float* __restrict__ b3,
    const unsigned short* __restrict__ wt,
    const int* __restrict__ csr_e, const int* __restrict__ csr_d,
    const int* __restrict__ edge_src, const int* __restrict__ edge_dst,
    float* __restrict__ out, int E) {
    __shared__ __align__(16) char sm[L_TOT];
    char* msg = sm + L_MSG;
    char* hbf = sm + L_H;
    int*  dl  = (int*)(sm + L_DST);

    const int tid  = threadIdx.x;
    const int lane = tid & 63;
    const int wv   = tid >> 6;    // 0..7
    const int l31  = lane & 31;
    const int hh   = lane >> 5;
    const int eb   = blockIdx.x * TM;

    // ---------- stage msg (bf16, swizzled); 8 threads per edge-row ----------
    {
        const int r   = tid >> 3;   // 0..63
        const int sub = tid & 7;
        const int slot = eb + r;
        const bool ok = slot < E;
        int e = 0, d = 0, s = 0;
        if (ok) {
            if (SORTED) { e = csr_e[slot]; d = csr_d[slot]; }
            else        { e = slot;        d = edge_dst[e]; }
            s = edge_src[e];
        }
        char* row = msg + r * MSTR;
#pragma unroll
        for (int i = 0; i < 2; i++) {
            const int c = 2 * sub + i;            // chunk 0..15 (8 feats each)
            uint4 v; v.x = v.y = v.z = v.w = 0u;
            if (ok) {
                const int cc = c & 7;
                if (BF16SRC) {
                    const char* base = (c < 8) ? (xb2 + (size_t)d * (2 * FDIM))
                                               : (xb1 + (size_t)s * (2 * FDIM));
                    v = *(const uint4*)(base + cc * 16);
                } else {
                    const float* base = (c < 8) ? (x2f + (size_t)d * FDIM)
                                                : (x1f + (size_t)s * FDIM);
                    float4 a = *(const float4*)(base + cc * 8);
                    float4 b = *(const float4*)(base + cc * 8 + 4);
                    v.x = pack2(a.x, a.y); v.y = pack2(a.z, a.w);
                    v.z = pack2(b.x, b.y); v.w = pack2(b.z, b.w);
                }
            }
            *(uint4*)(row + swz_msg(c, r) * 16) = v;
        }
        if (sub == 0) {
            dl[r] = ok ? d : -1;
            float dx = 0.f, dy = 0.f, dz = 0.f;
            if (ok) {
                dx = x1p[s * 3 + 0] - x2p[d * 3 + 0];
                dy = x1p[s * 3 + 1] - x2p[d * 3 + 1];
                dz = x1p[s * 3 + 2] - x2p[d * 3 + 2];
            }
            uint4 v; v.x = pack2(dx, dy); v.y = pack2(dz, 0.f); v.z = 0u; v.w = 0u;
            *(uint4*)(row + swz_msg(16, r) * 16) = v;   // feats 128..135
        } else if (sub == 1) {
            uint4 z; z.x = z.y = z.z = z.w = 0u;
            *(uint4*)(row + swz_msg(17, r) * 16) = z;   // feats 136..143
        }
    }
    __syncthreads();

    const int rt = wv & 3;        // feature tile (32 feats)
    const int ct = wv >> 2;       // edge tile (32 edges)

    // ---- layer 1: B from LDS msg (K=144) -> h1 into hbf ----
    {
        f32x16 acc = zerov();
#pragma unroll
        for (int ks = 0; ks < KS1; ks++) {
            bf16x8 A = *(const bf16x8*)(wt + (rt * 32 + l31) * K1 + ks * 16 + 8 * hh);
            const int r = ct * 32 + l31;
            bf16x8 B = *(const bf16x8*)(msg + r * MSTR + swz_msg(2 * ks + hh, r) * 16);
            acc = __builtin_amdgcn_mfma_f32_32x32x16_bf16(A, B, acc, 0, 0, 0);
        }
        tile_store<HSTR>(acc, b1, hbf, rt, ct, l31, hh);
    }
    __syncthreads();

    // ---- layer 2: reads hbf -> msg region (dead after L1) ----
    {
        f32x16 acc = layer128<HSTR>(wt + WT1_ELEMS, hbf, rt, ct, l31, hh);
        tile_store<MSTR>(acc, b2, msg, rt, ct, l31, hh);
    }
    __syncthreads();

    // ---- layer 3: reads msg region -> hbf ----
    {
        f32x16 acc = layer128<MSTR>(wt + WT1_ELEMS + WT2_ELEMS, msg, rt, ct, l31, hh);
        tile_store<HSTR>(acc, b3, hbf, rt, ct, l31, hh);
    }
    __syncthreads();

    // ---------- segment-max reduce (dst-sorted runs -> few atomics) ----------
    {
        const int feat  = tid & 127;  // one feature per thread
        const int strip = tid >> 7;   // 4 strips of 16 rows
        const int r0 = strip * 16;
        int curd = dl[r0];
        float m = 0.f;
        for (int r = r0; r < r0 + 16; r++) {
            int d = dl[r];
            if (d != curd) {
                if (curd >= 0 && m > 0.f)
                    atomicMax((int*)out + (size_t)curd * HH + feat, __float_as_int(m));
                curd = d; m = 0.f;
            }
            unsigned short w = *(const unsigned short*)(hbf + r * HSTR + swz_h(feat >> 3, r) * 16 + (feat & 7) * 2);
            m = fmaxf(m, __uint_as_float(((unsigned)w) << 16));
        }
        if (curd >= 0 && m > 0.f)
            atomicMax((int*)out + (size_t)curd * HH + feat, __float_as_int(m));
    }
}

extern "C" void kernel_launch(void* const* d_in, const int* in_sizes, int n_in,
                              void* d_out, int out_size, void* d_ws, size_t ws_size,
                              hipStream_t stream) {
    const float* x1f = (const float*)d_in[0];
    const float* x1p = (const float*)d_in[1];
    const float* x2f = (const float*)d_in[2];
    const float* x2p = (const float*)d_in[3];
    const float* W1  = (const float*)d_in[4];
    const float* b1  = (const float*)d_in[5];
    const float* W2  = (const float*)d_in[6];
    const float* b2  = (const float*)d_in[7];
    const float* W3  = (const float*)d_in[8];
    const float* b3  = (const float*)d_in[9];
    const int* esrc  = (const int*)d_in[10];
    const int* edst  = (const int*)d_in[11];
    const int E  = in_sizes[10];
    const int N1 = in_sizes[1] / 3;
    const int N2 = in_sizes[3] / 3;
    float* out = (float*)d_out;

    // workspace layout
    size_t off = 0;
    auto take = [&](size_t bytes) { size_t o = off; off = (off + bytes + 255) & ~(size_t)255; return o; };
    size_t o_cnt = take(4 * (size_t)N2);
    size_t o_cur = take(4 * (size_t)N2);
    size_t o_par = take(4 * 256);
    size_t o_ce  = take(4 * (size_t)E);
    size_t o_cd  = take(4 * (size_t)E);
    size_t o_wt  = take(2 * (size_t)WT_TOTAL);
    size_t need_csr = off;
    size_t o_x1  = take(2 * (size_t)N1 * FDIM);
    size_t o_x2  = take(2 * (size_t)N2 * FDIM);
    size_t need_bf = off;

    const int NB = (N2 + 1023) / 1024;
    bool use_csr = (need_csr <= ws_size) && (NB <= 256);
    bool use_bf  = (need_bf <= ws_size);

    char* ws = (char*)d_ws;
    unsigned short* wt = use_csr ? (unsigned short*)(ws + o_wt) : (unsigned short*)ws;
    int* cnt    = (int*)(ws + o_cnt);
    int* cursor = (int*)(ws + o_cur);
    int* part   = (int*)(ws + o_par);
    int* csr_e  = (int*)(ws + o_ce);
    int* csr_d  = (int*)(ws + o_cd);
    char* xb1   = ws + o_x1;
    char* xb2   = ws + o_x2;

    // output init: zero aggregate region, copy x2_pos into tail
    (void)hipMemsetAsync(out, 0, (size_t)N2 * HH * 4, stream);
    (void)hipMemcpyAsync(out + (size_t)N2 * HH, x2p, (size_t)N2 * 3 * 4,
                         hipMemcpyDeviceToDevice, stream);

    k_wprep<<<(WT_TOTAL + 255) / 256, 256, 0, stream>>>(W1, W2, W3, wt);

    if (use_bf) {
        int n8_1 = N1 * FDIM / 8, n8_2 = N2 * FDIM / 8;
        k_cvt<<<(n8_1 + 255) / 256, 256, 0, stream>>>(x1f, (unsigned short*)xb1, n8_1);
        k_cvt<<<(n8_2 + 255) / 256, 256, 0, stream>>>(x2f, (unsigned short*)xb2, n8_2);
    }

    const int grid = (E + TM - 1) / TM;
    if (use_csr) {
        (void)hipMemsetAsync(cnt, 0, 4 * (size_t)N2, stream);
        k_hist<<<(E + 255) / 256, 256, 0, stream>>>(edst, cnt, E);
        k_scan_part<<<NB, 256, 0, stream>>>(cnt, part, N2);
        k_scan_top<<<1, 256, 0, stream>>>(part, NB);
        k_scan_down<<<NB, 256, 0, stream>>>(cnt, part, cursor, N2);
        k_fill<<<(E + 255) / 256, 256, 0, stream>>>(edst, cursor, csr_e, csr_d, E);
        if (use_bf)
            k_main<true, true><<<grid, 512, 0, stream>>>(
                x1f, x1p, x2f, x2p, xb1, xb2, b1, b2, b3, wt, csr_e, csr_d, esrc, edst, out, E);
        else
            k_main<true, false><<<grid, 512, 0, stream>>>(
                x1f, x1p, x2f, x2p, xb1, xb2, b1, b2, b3, wt, csr_e, csr_d, esrc, edst, out, E);
    } else {
        if (use_bf)
            k_main<false, true><<<grid, 512, 0, stream>>>(
                x1f, x1p, x2f, x2p, xb1, xb2, b1, b2, b3, wt, edst, edst, esrc, edst, out, E);
        else
            k_main<false, false><<<grid, 512, 0, stream>>>(
                x1f, x1p, x2f, x2p, xb1, xb2, b1, b2, b3, wt, edst, edst, esrc, edst, out, E);
    }
}

// Round 6
// 596.738 us; speedup vs baseline: 1.5217x; 1.3819x over previous
//
#include <hip/hip_runtime.h>
#include <hip/hip_bf16.h>

#define DEV __device__ __forceinline__

typedef short bf16x8 __attribute__((ext_vector_type(8)));
typedef float f32x16 __attribute__((ext_vector_type(16)));

static constexpr int FDIM  = 64;
static constexpr int HH    = 128;           // hidden/out dim
static constexpr int K1RAW = 2 * FDIM + 3;  // 131
static constexpr int K1    = 144;           // padded K for layer 1 (mult of 16)
static constexpr int KS1   = K1 / 16;       // 9 k-steps
static constexpr int KS2   = HH / 16;       // 8 k-steps
static constexpr int TM    = 128;           // edges per block tile

static constexpr int MSTR  = 2 * K1;        // msg row stride bytes (288)
static constexpr int HSTR  = 2 * HH;        // h row stride bytes (256)
static constexpr int L_MSG = 0;
static constexpr int L_H   = TM * MSTR;            // 36864
static constexpr int L_DST = L_H + TM * HSTR;      // 69632
static constexpr int L_TOT = L_DST + TM * 4;       // 70144 -> 2 blocks/CU

static constexpr int WT1_ELEMS = HH * K1;          // 18432
static constexpr int WT2_ELEMS = HH * HH;          // 16384
static constexpr int WT_TOTAL  = WT1_ELEMS + 2 * WT2_ELEMS; // 51200

DEV unsigned pack2(float a, float b) {
    union { __hip_bfloat162 h; unsigned u; } cv;
    cv.h.x = __float2bfloat16(a);
    cv.h.y = __float2bfloat16(b);
    return cv.u;
}
DEV unsigned short f2bf(float f) {
    union { __hip_bfloat16 h; unsigned short u; } cv;
    cv.h = __float2bfloat16(f);
    return cv.u;
}
// chunk swizzle (16B chunks within a 288B row): chunks 0..15 XOR low-3 bits
// with row; chunks 16..17 XOR 1 bit (stay in range).
DEV int swz_msg(int c, int r) { const int m = (c < 16) ? 7 : 1; return (c & ~m) | ((c ^ r) & m); }
DEV int swz_h(int c, int r)   { return (c & ~7) | ((c ^ r) & 7); }

// ---------------- input bf16 conversion ----------------
__global__ void k_cvt(const float* __restrict__ src, unsigned short* __restrict__ dst, int n8) {
    int i = blockIdx.x * 256 + threadIdx.x;
    if (i < n8) {
        float4 a = *(const float4*)(src + (size_t)i * 8);
        float4 b = *(const float4*)(src + (size_t)i * 8 + 4);
        uint4 o;
        o.x = pack2(a.x, a.y); o.y = pack2(a.z, a.w);
        o.z = pack2(b.x, b.y); o.w = pack2(b.z, b.w);
        *(uint4*)(dst + (size_t)i * 8) = o;
    }
}

// ---------------- weight transpose + bf16 convert ----------------
__global__ void k_wprep(const float* __restrict__ W1, const float* __restrict__ W2,
                        const float* __restrict__ W3, unsigned short* __restrict__ wt) {
    int i = blockIdx.x * 256 + threadIdx.x;
    if (i < WT1_ELEMS) {
        int n = i / K1, k = i % K1;
        float v = (k < K1RAW) ? W1[k * HH + n] : 0.f;
        wt[i] = f2bf(v);
    } else if (i < WT1_ELEMS + WT2_ELEMS) {
        int j = i - WT1_ELEMS; int n = j / HH, k = j % HH;
        wt[i] = f2bf(W2[k * HH + n]);
    } else if (i < WT_TOTAL) {
        int j = i - WT1_ELEMS - WT2_ELEMS; int n = j / HH, k = j % HH;
        wt[i] = f2bf(W3[k * HH + n]);
    }
}

// ---------------- CSR build: hist -> scan -> fill ----------------
__global__ void k_hist(const int* __restrict__ edst, int* __restrict__ cnt, int E) {
    int e = blockIdx.x * 256 + threadIdx.x;
    if (e < E) atomicAdd(&cnt[edst[e]], 1);
}

__global__ void k_scan_part(const int* __restrict__ cnt, int* __restrict__ partial, int n2) {
    __shared__ int sm[256];
    int t = threadIdx.x;
    int base = blockIdx.x * 1024 + t * 4;
    int s = 0;
#pragma unroll
    for (int j = 0; j < 4; j++) { int idx = base + j; if (idx < n2) s += cnt[idx]; }
    sm[t] = s; __syncthreads();
    for (int off = 128; off > 0; off >>= 1) {
        if (t < off) sm[t] += sm[t + off];
        __syncthreads();
    }
    if (t == 0) partial[blockIdx.x] = sm[0];
}

__global__ void k_scan_top(int* __restrict__ partial, int nb) {
    __shared__ int sm[256];
    int t = threadIdx.x;
    int v = (t < nb) ? partial[t] : 0;
    sm[t] = v; __syncthreads();
    for (int off = 1; off < 256; off <<= 1) {
        int add = (t >= off) ? sm[t - off] : 0;
        __syncthreads();
        sm[t] += add;
        __syncthreads();
    }
    if (t < nb) partial[t] = sm[t] - v;   // exclusive
}

__global__ void k_scan_down(const int* __restrict__ cnt, const int* __restrict__ partial,
                            int* __restrict__ cursor, int n2) {
    __shared__ int sm[256];
    int t = threadIdx.x;
    int base = blockIdx.x * 1024 + t * 4;
    int c[4]; int s = 0;
#pragma unroll
    for (int j = 0; j < 4; j++) { int idx = base + j; c[j] = (idx < n2) ? cnt[idx] : 0; s += c[j]; }
    sm[t] = s; __syncthreads();
    for (int off = 1; off < 256; off <<= 1) {
        int add = (t >= off) ? sm[t - off] : 0;
        __syncthreads();
        sm[t] += add;
        __syncthreads();
    }
    int run = partial[blockIdx.x] + (sm[t] - s);
#pragma unroll
    for (int j = 0; j < 4; j++) {
        int idx = base + j;
        if (idx < n2) cursor[idx] = run;
        run += c[j];
    }
}

__global__ void k_fill(const int* __restrict__ edst, int* __restrict__ cursor,
                       int* __restrict__ csr_e, int* __restrict__ csr_d, int E) {
    int e = blockIdx.x * 256 + threadIdx.x;
    if (e < E) {
        int d = edst[e];
        int p = atomicAdd(&cursor[d], 1);
        csr_e[p] = e;
        csr_d[p] = d;
    }
}

// ---------------- fused MLP + segment-max ----------------
DEV f32x16 zerov() {
    f32x16 v;
#pragma unroll
    for (int i = 0; i < 16; i++) v[i] = 0.f;
    return v;
}

// store one wave's 32x32 acc tile (bias+ReLU+bf16) into LDS buffer
template <int STRIDE>
DEV void tile_store(const f32x16& acc, const float* __restrict__ bias, char* __restrict__ hb,
                    int rt, int ct, int l31, int hh) {
    const int r = ct * 32 + l31;
#pragma unroll
    for (int g = 0; g < 4; g++) {
        // regs 4g..4g+3 hold features rt*32 + 8g + 4hh + {0..3}
        float4 bv = *(const float4*)(bias + rt * 32 + 8 * g + 4 * hh);
        float v0 = fmaxf(acc[4 * g + 0] + bv.x, 0.f);
        float v1 = fmaxf(acc[4 * g + 1] + bv.y, 0.f);
        float v2 = fmaxf(acc[4 * g + 2] + bv.z, 0.f);
        float v3 = fmaxf(acc[4 * g + 3] + bv.w, 0.f);
        uint2 w; w.x = pack2(v0, v1); w.y = pack2(v2, v3);
        *(uint2*)(hb + r * STRIDE + swz_h(4 * rt + g, r) * 16 + 8 * hh) = w;
    }
}

// one layer for one wave: prefetch all A-frags, then per edge-tile prefetch
// all B-frags and run the MFMA chain. KSTEPS known at compile time.
template <int KSTEPS, int STRIDE, bool MSG, int OSTRIDE>
DEV void layer(const unsigned short* __restrict__ wtl, const char* __restrict__ src,
               const float* __restrict__ bias, char* __restrict__ dst,
               int rt, int ct0, int l31, int hh) {
    bf16x8 A[KSTEPS];
#pragma unroll
    for (int ks = 0; ks < KSTEPS; ks++)
        A[ks] = *(const bf16x8*)(wtl + (rt * 32 + l31) * (KSTEPS * 16) + ks * 16 + 8 * hh);
#pragma unroll
    for (int j = 0; j < 2; j++) {
        const int r = (ct0 + j) * 32 + l31;
        bf16x8 B[KSTEPS];
#pragma unroll
        for (int ks = 0; ks < KSTEPS; ks++) {
            const int c = 2 * ks + hh;
            const int cs = MSG ? swz_msg(c, r) : swz_h(c, r);
            B[ks] = *(const bf16x8*)(src + r * STRIDE + cs * 16);
        }
        f32x16 acc = zerov();
#pragma unroll
        for (int ks = 0; ks < KSTEPS; ks++)
            acc = __builtin_amdgcn_mfma_f32_32x32x16_bf16(A[ks], B[ks], acc, 0, 0, 0);
        tile_store<OSTRIDE>(acc, bias, dst, rt, ct0 + j, l31, hh);
    }
}

template <bool SORTED, bool BF16SRC>
__global__ __launch_bounds__(512, 4) void k_main(
    const float* __restrict__ x1f, const float* __restrict__ x1p,
    const float* __restrict__ x2f, const float* __restrict__ x2p,
    const char* __restrict__ xb1, const char* __restrict__ xb2,
    const float* __restrict__ b1, const float* __restrict__ b2, const float* __restrict__ b3,
    const unsigned short* __restrict__ wt,
    const int* __restrict__ csr_e, const int* __restrict__ csr_d,
    const int* __restrict__ edge_src, const int* __restrict__ edge_dst,
    float* __restrict__ out, int E) {
    __shared__ __align__(16) char sm[L_TOT];
    char* msg = sm + L_MSG;
    char* hbf = sm + L_H;
    int*  dl  = (int*)(sm + L_DST);

    const int tid  = threadIdx.x;
    const int lane = tid & 63;
    const int wv   = tid >> 6;    // 0..7
    const int l31  = lane & 31;
    const int hh   = lane >> 5;
    const int eb   = blockIdx.x * TM;

    // ---------- stage msg (bf16, swizzled); 4 threads per edge-row ----------
    {
        const int r   = tid >> 2;   // 0..127
        const int sub = tid & 3;
        const int slot = eb + r;
        const bool ok = slot < E;
        int e = 0, d = 0, s = 0;
        if (ok) {
            if (SORTED) { e = csr_e[slot]; d = csr_d[slot]; }
            else        { e = slot;        d = edge_dst[e]; }
            s = edge_src[e];
        }
        if (sub == 0) dl[r] = ok ? d : -1;
        char* row = msg + r * MSTR;
        const int c0 = sub * 4;
#pragma unroll
        for (int i = 0; i < 4; i++) {
            const int c = c0 + i;                 // chunk 0..15 (8 feats each)
            uint4 v; v.x = v.y = v.z = v.w = 0u;
            if (ok) {
                const int cc = c & 7;
                if (BF16SRC) {
                    const char* base = (c < 8) ? (xb2 + (size_t)d * (2 * FDIM))
                                               : (xb1 + (size_t)s * (2 * FDIM));
                    v = *(const uint4*)(base + cc * 16);
                } else {
                    const float* base = (c < 8) ? (x2f + (size_t)d * FDIM)
                                                : (x1f + (size_t)s * FDIM);
                    float4 a = *(const float4*)(base + cc * 8);
                    float4 b = *(const float4*)(base + cc * 8 + 4);
                    v.x = pack2(a.x, a.y); v.y = pack2(a.z, a.w);
                    v.z = pack2(b.x, b.y); v.w = pack2(b.z, b.w);
                }
            }
            *(uint4*)(row + swz_msg(c, r) * 16) = v;
        }
        if (sub == 3) {
            float dx = 0.f, dy = 0.f, dz = 0.f;
            if (ok) {
                dx = x1p[s * 3 + 0] - x2p[d * 3 + 0];
                dy = x1p[s * 3 + 1] - x2p[d * 3 + 1];
                dz = x1p[s * 3 + 2] - x2p[d * 3 + 2];
            }
            uint4 v; v.x = pack2(dx, dy); v.y = pack2(dz, 0.f); v.z = 0u; v.w = 0u;
            *(uint4*)(row + swz_msg(16, r) * 16) = v;   // feats 128..135
            uint4 z; z.x = z.y = z.z = z.w = 0u;
            *(uint4*)(row + swz_msg(17, r) * 16) = z;   // feats 136..143
        }
    }
    __syncthreads();

    const int rt  = wv & 3;         // feature tile (32 feats)
    const int ct0 = (wv >> 2) * 2;  // edge tile pair base

    // ---- layer 1: msg (K=144) -> hbf ----
    layer<KS1, MSTR, true, HSTR>(wt, msg, b1, hbf, rt, ct0, l31, hh);
    __syncthreads();
    // ---- layer 2: hbf -> msg region (dead after L1) ----
    layer<KS2, HSTR, false, MSTR>(wt + WT1_ELEMS, hbf, b2, msg, rt, ct0, l31, hh);
    __syncthreads();
    // ---- layer 3: msg region -> hbf ----
    layer<KS2, MSTR, false, HSTR>(wt + WT1_ELEMS + WT2_ELEMS, msg, b3, hbf, rt, ct0, l31, hh);
    __syncthreads();

    // ---------- segment-max: interior runs -> plain store, boundary -> atomic ----
    {
        const int feat  = tid & 127;  // one feature per thread
        const int strip = tid >> 7;   // 4 strips of 32 rows
        const int r0 = strip * 32;
        int curd = dl[r0];
        int rs = r0;                  // current run start
        float m = 0.f;
#pragma unroll
        for (int b = 0; b < 4; b++) {
            float vals[8];
            int   ds[8];
#pragma unroll
            for (int j = 0; j < 8; j++) {
                const int r = r0 + b * 8 + j;
                unsigned short w = *(const unsigned short*)(
                    hbf + r * HSTR + swz_h(feat >> 3, r) * 16 + (feat & 7) * 2);
                vals[j] = __uint_as_float(((unsigned)w) << 16);
                ds[j]   = dl[r];
            }
#pragma unroll
            for (int j = 0; j < 8; j++) {
                const int r = r0 + b * 8 + j;
                const int d = ds[j];
                if (d != curd) {
                    if (curd >= 0) {
                        // run [rs, r-1]; end is interior (r-1 < r0+31 here)
                        bool extL = (rs == r0) && (r0 == 0 || dl[r0 - 1] == curd);
                        if (extL) {
                            if (m > 0.f)
                                atomicMax((int*)out + (size_t)curd * HH + feat, __float_as_int(m));
                        } else {
                            out[(size_t)curd * HH + feat] = m;
                        }
                    }
                    curd = d; rs = r; m = 0.f;
                }
                m = fmaxf(m, vals[j]);
            }
        }
        if (curd >= 0) {
            // final run ends at r0+31 -> may extend right
            bool extL = (rs == r0) && (r0 == 0 || dl[r0 - 1] == curd);
            bool extR = (r0 + 32 == TM) || (dl[r0 + 32] == curd);
            if (extL || extR) {
                if (m > 0.f)
                    atomicMax((int*)out + (size_t)curd * HH + feat, __float_as_int(m));
            } else {
                out[(size_t)curd * HH + feat] = m;
            }
        }
    }
}

extern "C" void kernel_launch(void* const* d_in, const int* in_sizes, int n_in,
                              void* d_out, int out_size, void* d_ws, size_t ws_size,
                              hipStream_t stream) {
    const float* x1f = (const float*)d_in[0];
    const float* x1p = (const float*)d_in[1];
    const float* x2f = (const float*)d_in[2];
    const float* x2p = (const float*)d_in[3];
    const float* W1  = (const float*)d_in[4];
    const float* b1  = (const float*)d_in[5];
    const float* W2  = (const float*)d_in[6];
    const float* b2  = (const float*)d_in[7];
    const float* W3  = (const float*)d_in[8];
    const float* b3  = (const float*)d_in[9];
    const int* esrc  = (const int*)d_in[10];
    const int* edst  = (const int*)d_in[11];
    const int E  = in_sizes[10];
    const int N1 = in_sizes[1] / 3;
    const int N2 = in_sizes[3] / 3;
    float* out = (float*)d_out;

    // workspace layout
    size_t off = 0;
    auto take = [&](size_t bytes) { size_t o = off; off = (off + bytes + 255) & ~(size_t)255; return o; };
    size_t o_cnt = take(4 * (size_t)N2);
    size_t o_cur = take(4 * (size_t)N2);
    size_t o_par = take(4 * 256);
    size_t o_ce  = take(4 * (size_t)E);
    size_t o_cd  = take(4 * (size_t)E);
    size_t o_wt  = take(2 * (size_t)WT_TOTAL);
    size_t need_csr = off;
    size_t o_x1  = take(2 * (size_t)N1 * FDIM);
    size_t o_x2  = take(2 * (size_t)N2 * FDIM);
    size_t need_bf = off;

    const int NB = (N2 + 1023) / 1024;
    bool use_csr = (need_csr <= ws_size) && (NB <= 256);
    bool use_bf  = (need_bf <= ws_size);

    char* ws = (char*)d_ws;
    unsigned short* wt = use_csr ? (unsigned short*)(ws + o_wt) : (unsigned short*)ws;
    int* cnt    = (int*)(ws + o_cnt);
    int* cursor = (int*)(ws + o_cur);
    int* part   = (int*)(ws + o_par);
    int* csr_e  = (int*)(ws + o_ce);
    int* csr_d  = (int*)(ws + o_cd);
    char* xb1   = ws + o_x1;
    char* xb2   = ws + o_x2;

    // output init: zero aggregate region, copy x2_pos into tail
    (void)hipMemsetAsync(out, 0, (size_t)N2 * HH * 4, stream);
    (void)hipMemcpyAsync(out + (size_t)N2 * HH, x2p, (size_t)N2 * 3 * 4,
                         hipMemcpyDeviceToDevice, stream);

    k_wprep<<<(WT_TOTAL + 255) / 256, 256, 0, stream>>>(W1, W2, W3, wt);

    if (use_bf) {
        int n8_1 = N1 * FDIM / 8, n8_2 = N2 * FDIM / 8;
        k_cvt<<<(n8_1 + 255) / 256, 256, 0, stream>>>(x1f, (unsigned short*)xb1, n8_1);
        k_cvt<<<(n8_2 + 255) / 256, 256, 0, stream>>>(x2f, (unsigned short*)xb2, n8_2);
    }

    const int grid = (E + TM - 1) / TM;
    if (use_csr) {
        (void)hipMemsetAsync(cnt, 0, 4 * (size_t)N2, stream);
        k_hist<<<(E + 255) / 256, 256, 0, stream>>>(edst, cnt, E);
        k_scan_part<<<NB, 256, 0, stream>>>(cnt, part, N2);
        k_scan_top<<<1, 256, 0, stream>>>(part, NB);
        k_scan_down<<<NB, 256, 0, stream>>>(cnt, part, cursor, N2);
        k_fill<<<(E + 255) / 256, 256, 0, stream>>>(edst, cursor, csr_e, csr_d, E);
        if (use_bf)
            k_main<true, true><<<grid, 512, 0, stream>>>(
                x1f, x1p, x2f, x2p, xb1, xb2, b1, b2, b3, wt, csr_e, csr_d, esrc, edst, out, E);
        else
            k_main<true, false><<<grid, 512, 0, stream>>>(
                x1f, x1p, x2f, x2p, xb1, xb2, b1, b2, b3, wt, csr_e, csr_d, esrc, edst, out, E);
    } else {
        if (use_bf)
            k_main<false, true><<<grid, 512, 0, stream>>>(
                x1f, x1p, x2f, x2p, xb1, xb2, b1, b2, b3, wt, edst, edst, esrc, edst, out, E);
        else
            k_main<false, false><<<grid, 512, 0, stream>>>(
                x1f, x1p, x2f, x2p, xb1, xb2, b1, b2, b3, wt, edst, edst, esrc, edst, out, E);
    }
}